// Round 12
// baseline (245.010 us; speedup 1.0000x reference)
//
#include <hip/hip_runtime.h>

#define T 4
#define D 1024
#define NN 256
#define K 64
#define V 32000
// derived
#define VK (V*K)          // 2048000
#define TD (T*D)          // 4096
#define NB 32             // buckets per t (1000-word ranges)
#define CAP 1024          // tokens per (t,bucket32,slice16) segment; mean ~350, 36-sigma safe

__device__ __forceinline__ float jexp(float x) {
    // jax_exp: clip(exp(clip(x,-700,700)), 1e-6)
    x = fminf(fmaxf(x, -700.0f), 700.0f);
    return fmaxf(expf(x), 1e-6f);
}

// ws layout: S f32[256] | S_part f32[500*64] | resv u32[2048] | list u32[2048*CAP] (8MB)
// R11 (resubmit; prior round was an infra failure, kernel never ran):
// cwk + phi_update merged. Each block replays all-4-t lists for its 125-row
// window into 64KB LDS histograms, then runs the t-chained phi sweep decoding
// the histograms directly: CWK_new written once, never re-read (-32MB), -1 launch.

// ---------------- fused: colsum role (500 blocks) + eta/MH role (4096 blocks) ----
__global__ void fused_kernel(const int* __restrict__ W, const int* __restrict__ Z,
                             const int* __restrict__ pwi, const int* __restrict__ ptop,
                             const float* __restrict__ u, const float* __restrict__ phi,
                             const float* __restrict__ eta,
                             const float* __restrict__ alpha,
                             const float* __restrict__ noise_eta,
                             const float* __restrict__ CDK,
                             const float* __restrict__ CK,
                             float* __restrict__ S_part,
                             float* __restrict__ CK_new,
                             float* __restrict__ eta_new,
                             float* __restrict__ CDK_new,
                             unsigned int* __restrict__ resv,
                             unsigned int* __restrict__ list,
                             float* __restrict__ z_out)
{
    int blk = blockIdx.x;
    int n = threadIdx.x;

    __shared__ float sm[256];       // colsum role
    __shared__ float esh[K];        // mh role
    __shared__ int   hist[K];
    __shared__ int   bcnt[NB];
    __shared__ int   bbase[NB];

    if (blk < 500) {
        // ================= colsum role =================
        if (blk == 0) CK_new[n] = CK[n];        // T*K = 256 = blockDim
        int t = blk / 125;
        int vbase = (blk % 125) * 256;
        int k = n & 63;
        int rr = n >> 6;            // 0..3
        const float* base = phi + (size_t)t * VK;
        float s = 0.0f;
        #pragma unroll 4
        for (int it = 0; it < 64; ++it) {
            int v = vbase + it * 4 + rr;
            s += expf(base[v * K + k]);         // coalesced
        }
        sm[n] = s;
        __syncthreads();
        if (n < 64) {
            S_part[blk * 64 + n] = sm[n] + sm[n + 64] +
                                   sm[n + 128] + sm[n + 192];
        }
        return;
    }

    // ================= eta + MH role =================
    int b = blk - 500;                   // 500 % 8 == 4: (b&7)->XCD still bijective
    int r = ((b & 7) << 9) | (b >> 3);   // XCD-locality: one t per XCD-class
    int t = r >> 10;                     // D = 1024
    int slice = (b >> 3) & 15;           // reservation-contention striping

    // ---- early independent token loads (issue before the eta barrier) ----
    int w     = W[r * NN + n];
    int pre   = Z[r * NN + n];          // coalesced; makes the row L1-hot
    int pw    = pwi[r * NN + n];
    int prop1 = Z[r * NN + pw];         // random-in-row: L1 hit
    int pt    = ptop[r * NN + n];
    float2 uu = ((const float2*)u)[(size_t)r * NN + n];

    const float* prow = phi + ((size_t)t * V + w) * K;
    float f1 = prow[prop1];             // scattered gathers, in flight during eta
    float f0 = prow[pre];

    float cdk = 0.0f;
    if (n < 64) {
        // ---- eta SGLD update for this row, wave 0 only ----
        float x = eta[r * K + n];
        float m = x;
        #pragma unroll
        for (int off = 32; off >= 1; off >>= 1)
            m = fmaxf(m, __shfl_xor(m, off, 64));
        float e = expf(x - m);
        float s = e;
        #pragma unroll
        for (int off = 32; off >= 1; off >>= 1)
            s += __shfl_xor(s, off, 64);
        float smx = e / s;
        cdk = CDK[r * K + n];
        float grad  = cdk - (float)NN * smx;
        float prior = alpha[t * K + n] - x;          // ETA_VAR = 1
        float en = x + 0.005f * (grad + prior) + noise_eta[r] * 0.01f;
        esh[n] = en;
        eta_new[r * K + n] = en;
    } else if (n < 128) {
        hist[n - 64] = 0;
    } else if (n < 128 + NB) {
        bcnt[n - 128] = 0;
    }
    __syncthreads();

    float a1 = jexp(f1) / jexp(f0);
    int k1 = (uu.x < a1) ? prop1 : pre;

    float a2 = jexp(esh[pt]) / jexp(esh[k1]);
    int z = (uu.y < a2) ? pt : k1;

    // LDS-only work before barriers
    atomicAdd(&hist[z], 1);
    atomicAdd(&hist[pre], -1);

    int keep = (z != pre);
    int bucket = w / 1000;              // 0..31, 1000-word ranges
    int myidx = 0;
    if (keep) myidx = atomicAdd(&bcnt[bucket], 1);
    __syncthreads();

    if (n < NB) {
        // one small global reservation atomic per (block,bucket); 2048 counters
        bbase[n] = (int)atomicAdd(&resv[(t * NB + n) * 16 + slice],
                                  (unsigned int)bcnt[n]);
    }
    __syncthreads();

    // ---- phase C: global writes, fire-and-forget ----
    z_out[r * NN + n] = (float)z;
    if (keep) {
        int slot = bbase[bucket] + myidx;
        if (slot < CAP) {
            unsigned int pk = (unsigned int)w | ((unsigned int)z << 15) |
                              ((unsigned int)pre << 21);
            list[(size_t)((t * NB + bucket) * 16 + slice) * CAP + slot] = pk;
        }
    }
    if (n < K) {
        CDK_new[r * K + n] = cdk + (float)hist[n];   // block owns this row
    }
}

// ---------------- S finalize + CK_new += sum_d (CDKn - CDK) ----------------
// grid = 64 blocks (16 per t), 256 threads; CK_new pre-initialized with CK.
__global__ void reduce_kernel(const float* __restrict__ S_part,
                              const float* __restrict__ CDKn,
                              const float* __restrict__ CDK,
                              float* __restrict__ S,
                              float* __restrict__ CK_new)
{
    int b = blockIdx.x;
    int tid = threadIdx.x;

    if (b < 4 && tid < 64) {            // S finalize for t = b
        float s = 0.0f;
        #pragma unroll 5
        for (int i = 0; i < 125; ++i)
            s += S_part[(b * 125 + i) * 64 + tid];
        S[b * 64 + tid] = s;
    }

    int t  = b >> 4;
    int k  = tid & 63;
    int dl = tid >> 6;                  // 0..3
    int dbase = (b & 15) << 6;          // 16 chunks of 64 d's per t
    float s = 0.0f;
    #pragma unroll
    for (int i = 0; i < 16; ++i) {
        int d = dbase + dl + (i << 2);
        size_t idx = ((size_t)(t << 10) + d) * 64 + k;
        s += CDKn[idx] - CDK[idx];
    }
    __shared__ float sm[256];
    sm[tid] = s;
    __syncthreads();
    if (tid < 64) {
        float tot = sm[k] + sm[k + 64] + sm[k + 128] + sm[k + 192];
        if (tot != 0.0f) atomicAdd(&CK_new[(t << 6) + k], tot);
    }
}

// ---------------- merged: list replay (all 4 t) + phi SGLD + CWK_new ----------------
// grid = 256 blocks: bucket = b&31, window = b>>5 (8 windows of 125 rows/bucket).
// b%8 = bucket%8 -> all windows of one bucket pin to one XCD (L2-local list scans).
// LDS: 4 x (plus,minus) histograms of 125 rows x 16 u32 = 64000 B (fits 64KB).
__global__ void cwkphi_kernel(const unsigned int* __restrict__ list,
                              const unsigned int* __restrict__ resv,
                              const float* __restrict__ CWK,
                              const float* __restrict__ phi,
                              const float* __restrict__ CKn,
                              const float* __restrict__ S,
                              const float* __restrict__ noise_phi,
                              float* __restrict__ CWK_new,
                              float* __restrict__ phi_new)
{
    int b = blockIdx.x;
    int bucket = b & 31;
    int window = b >> 5;                // 0..7
    int vbase = bucket * 1000 + window * 125;

    __shared__ unsigned int plusH[4][2000];     // [t][row*16 + kg], u8 x4 packed
    __shared__ unsigned int minusH[4][2000];
    for (int i = threadIdx.x; i < 2000; i += 256) {
        plusH[0][i] = 0u; plusH[1][i] = 0u; plusH[2][i] = 0u; plusH[3][i] = 0u;
        minusH[0][i] = 0u; minusH[1][i] = 0u; minusH[2][i] = 0u; minusH[3][i] = 0u;
    }
    __syncthreads();

    int wave = threadIdx.x >> 6;
    int lane = threadIdx.x & 63;

#define DECODE(PK, TT) {                                                          \
        int wv = (int)((PK) & 32767u);                                            \
        unsigned int vl = (unsigned int)(wv - vbase);                             \
        if (vl < 125u) {                                                          \
            int zz = (int)(((PK) >> 15) & 63u);                                   \
            int pr = (int)(((PK) >> 21) & 63u);                                   \
            atomicAdd(&plusH [TT][vl * 16 + (zz >> 2)], 1u << ((zz & 3) * 8));    \
            atomicAdd(&minusH[TT][vl * 16 + (pr >> 2)], 1u << ((pr & 3) * 8));    \
        } }

    // 64 segments (4 t x 16 slices), waves take disjoint strided segments
    for (int ss = wave; ss < 64; ss += 4) {
        int t = ss >> 4;
        int s = ss & 15;
        int seg = (t * NB + bucket) * 16 + s;
        int len = (int)resv[seg]; if (len > CAP) len = CAP;
        const unsigned int* lp = list + (size_t)seg * CAP;
        const uint4* lp4 = (const uint4*)lp;
        int n4 = len >> 2;
        for (int i = lane; i < n4; i += 64) {
            uint4 q = lp4[i];
            DECODE(q.x, t); DECODE(q.y, t); DECODE(q.z, t); DECODE(q.w, t);
        }
        int base4 = n4 << 2;
        if (lane < (len & 3)) { unsigned int pk = lp[base4 + lane]; DECODE(pk, t); }
    }
#undef DECODE
    __syncthreads();

    // ---- t-chained phi sweep over 125 rows x 64 k = 2000 float4 per t ----
    const float eps = 0.01f;
    const float half_eps = 0.005f;
    const float sig = 1.0f / 1.01f;             // phi_sigma / PHI_VAR

    const float4* phi4  = (const float4*)phi;
    const float4* cwk4  = (const float4*)CWK;
    const float4* ck4   = (const float4*)CKn;
    const float4* s4    = (const float4*)S;
    float4*       pout4 = (float4*)phi_new;
    float4*       cout4 = (float4*)CWK_new;

    float np0 = noise_phi[0] * eps, np1 = noise_phi[1] * eps;
    float np2 = noise_phi[2] * eps, np3 = noise_phi[3] * eps;

    size_t base4 = (size_t)vbase * 16;          // float4 offset of window within a t

    for (int i4 = threadIdx.x; i4 < 2000; i4 += 256) {
        int kg = i4 & 15;
        size_t g = base4 + i4;

        float4 p0 = phi4[g];
        float4 p1 = phi4[g +     512000];
        float4 p2 = phi4[g + 2 * 512000];
        float4 p3 = phi4[g + 3 * 512000];

        float4 c0 = cwk4[g];
        float4 c1 = cwk4[g +     512000];
        float4 c2 = cwk4[g + 2 * 512000];
        float4 c3 = cwk4[g + 3 * 512000];

        unsigned int pl0 = plusH[0][i4], mi0 = minusH[0][i4];
        unsigned int pl1 = plusH[1][i4], mi1 = minusH[1][i4];
        unsigned int pl2 = plusH[2][i4], mi2 = minusH[2][i4];
        unsigned int pl3 = plusH[3][i4], mi3 = minusH[3][i4];

        float4 ckn0 = ck4[kg],      ckn1 = ck4[16 + kg];
        float4 ckn2 = ck4[32 + kg], ckn3 = ck4[48 + kg];
        float4 ss0 = s4[kg],        ss1 = s4[16 + kg];
        float4 ss2 = s4[32 + kg],   ss3 = s4[48 + kg];

        float4 o0, o1, o2, o3, w0, w1, w2, w3;
        #pragma unroll
        for (int j = 0; j < 4; ++j) {
            int sh = j * 8;
            float q0 = (&p0.x)[j], q1 = (&p1.x)[j], q2 = (&p2.x)[j], q3 = (&p3.x)[j];
            float cw0 = (&c0.x)[j] + (float)((pl0 >> sh) & 255u) - (float)((mi0 >> sh) & 255u);
            float cw1 = (&c1.x)[j] + (float)((pl1 >> sh) & 255u) - (float)((mi1 >> sh) & 255u);
            float cw2 = (&c2.x)[j] + (float)((pl2 >> sh) & 255u) - (float)((mi2 >> sh) & 255u);
            float cw3 = (&c3.x)[j] + (float)((pl3 >> sh) & 255u) - (float)((mi3 >> sh) & 255u);
            (&w0.x)[j] = cw0; (&w1.x)[j] = cw1; (&w2.x)[j] = cw2; (&w3.x)[j] = cw3;

            float g0 = cw0 - (&ckn0.x)[j] * (expf(q0) / (&ss0.x)[j]);
            float g1 = cw1 - (&ckn1.x)[j] * (expf(q1) / (&ss1.x)[j]);
            float g2 = cw2 - (&ckn2.x)[j] * (expf(q2) / (&ss2.x)[j]);
            float g3 = cw3 - (&ckn3.x)[j] * (expf(q3) / (&ss3.x)[j]);

            float r0 = q0 + half_eps * (g0 + 2.0f * q1 * sig - 2.0f * q0) + np0;
            float r1 = q1 + half_eps * (g1 + q2 + r0 - 2.0f * q1)         + np1;
            float r2 = q2 + half_eps * (g2 + q3 + r1 - 2.0f * q2)         + np2;
            float r3 = q3 + half_eps * (g3 + r2 - q3)                      + np3;

            (&o0.x)[j] = r0; (&o1.x)[j] = r1; (&o2.x)[j] = r2; (&o3.x)[j] = r3;
        }

        pout4[g]              = o0;
        pout4[g +     512000] = o1;
        pout4[g + 2 * 512000] = o2;
        pout4[g + 3 * 512000] = o3;

        cout4[g]              = w0;
        cout4[g +     512000] = w1;
        cout4[g + 2 * 512000] = w2;
        cout4[g + 3 * 512000] = w3;
    }
}

extern "C" void kernel_launch(void* const* d_in, const int* in_sizes, int n_in,
                              void* d_out, int out_size, void* d_ws, size_t ws_size,
                              hipStream_t stream)
{
    const int*   W         = (const int*)  d_in[0];
    const int*   Z         = (const int*)  d_in[1];
    const int*   pwi       = (const int*)  d_in[2];
    const int*   ptop      = (const int*)  d_in[3];
    const float* u_mh      = (const float*)d_in[4];
    const float* noise_eta = (const float*)d_in[5];
    const float* noise_phi = (const float*)d_in[6];
    const float* alpha     = (const float*)d_in[7];
    const float* phi       = (const float*)d_in[8];
    const float* eta       = (const float*)d_in[9];
    const float* CDK       = (const float*)d_in[10];
    const float* CWK       = (const float*)d_in[11];
    const float* CK        = (const float*)d_in[12];

    float* out     = (float*)d_out;
    float* eta_new = out;                               // T*D*K   = 262144
    float* phi_new = out + 262144;                      // T*V*K   = 8192000
    float* CDK_new = out + 8454144;                     // T*D*K   = 262144
    float* CWK_new = out + 8716288;                     // T*V*K   = 8192000
    float* CK_new  = out + 16908288;                    // T*K     = 256
    float* z_out   = out + 16908544;                    // T*D*N   = 1048576

    float* ws      = (float*)d_ws;
    float* S       = ws;                                // 256 floats
    float* S_part  = ws + 256;                          // 500*64 floats
    unsigned int* resv = (unsigned int*)(ws + 256 + 32000);    // 2048 u32
    unsigned int* list = resv + 2048;                          // 2048*CAP u32 = 8MB

    hipMemsetAsync(resv, 0, 2048 * sizeof(unsigned int), stream);

    fused_kernel<<<500 + TD, 256, 0, stream>>>(W, Z, pwi, ptop, u_mh, phi,
                                               eta, alpha, noise_eta, CDK, CK,
                                               S_part, CK_new,
                                               eta_new, CDK_new, resv, list, z_out);
    reduce_kernel<<<64, 256, 0, stream>>>(S_part, CDK_new, CDK, S, CK_new);
    cwkphi_kernel<<<256, 256, 0, stream>>>(list, resv, CWK, phi, CK_new, S,
                                           noise_phi, CWK_new, phi_new);
}

// Round 13
// 217.478 us; speedup vs baseline: 1.1266x; 1.1266x over previous
//
#include <hip/hip_runtime.h>

#define T 4
#define D 1024
#define NN 256
#define K 64
#define V 32000
// derived
#define VK (V*K)          // 2048000
#define TD (T*D)          // 4096
#define NB 32             // buckets per t (1000-word ranges)
#define CAP 1024          // tokens per (t,bucket32,slice16) segment; mean ~350, 36-sigma safe

__device__ __forceinline__ float jexp(float x) {
    // jax_exp: clip(exp(clip(x,-700,700)), 1e-6)
    x = fminf(fmaxf(x, -700.0f), 700.0f);
    return fmaxf(expf(x), 1e-6f);
}

// ws layout: S f32[256] | S_part f32[500*64] | resv u32[2048] | list u32[2048*CAP] (8MB)
// R13: R12's merged cwkphi regressed (64us @ 9% occupancy: 64KB LDS + 256 blocks
// = 1 block/CU x 4 waves). Grid is geometry-pinned (all-4-t per block for the
// t-chain), so raise waves/block instead: blockDim 256 -> 1024 = 16 waves/CU (50%).

// ---------------- fused: colsum role (500 blocks) + eta/MH role (4096 blocks) ----
__global__ void fused_kernel(const int* __restrict__ W, const int* __restrict__ Z,
                             const int* __restrict__ pwi, const int* __restrict__ ptop,
                             const float* __restrict__ u, const float* __restrict__ phi,
                             const float* __restrict__ eta,
                             const float* __restrict__ alpha,
                             const float* __restrict__ noise_eta,
                             const float* __restrict__ CDK,
                             const float* __restrict__ CK,
                             float* __restrict__ S_part,
                             float* __restrict__ CK_new,
                             float* __restrict__ eta_new,
                             float* __restrict__ CDK_new,
                             unsigned int* __restrict__ resv,
                             unsigned int* __restrict__ list,
                             float* __restrict__ z_out)
{
    int blk = blockIdx.x;
    int n = threadIdx.x;

    __shared__ float sm[256];       // colsum role
    __shared__ float esh[K];        // mh role
    __shared__ int   hist[K];
    __shared__ int   bcnt[NB];
    __shared__ int   bbase[NB];

    if (blk < 500) {
        // ================= colsum role =================
        if (blk == 0) CK_new[n] = CK[n];        // T*K = 256 = blockDim
        int t = blk / 125;
        int vbase = (blk % 125) * 256;
        int k = n & 63;
        int rr = n >> 6;            // 0..3
        const float* base = phi + (size_t)t * VK;
        float s = 0.0f;
        #pragma unroll 4
        for (int it = 0; it < 64; ++it) {
            int v = vbase + it * 4 + rr;
            s += expf(base[v * K + k]);         // coalesced
        }
        sm[n] = s;
        __syncthreads();
        if (n < 64) {
            S_part[blk * 64 + n] = sm[n] + sm[n + 64] +
                                   sm[n + 128] + sm[n + 192];
        }
        return;
    }

    // ================= eta + MH role =================
    int b = blk - 500;                   // 500 % 8 == 4: (b&7)->XCD still bijective
    int r = ((b & 7) << 9) | (b >> 3);   // XCD-locality: one t per XCD-class
    int t = r >> 10;                     // D = 1024
    int slice = (b >> 3) & 15;           // reservation-contention striping

    // ---- early independent token loads (issue before the eta barrier) ----
    int w     = W[r * NN + n];
    int pre   = Z[r * NN + n];          // coalesced; makes the row L1-hot
    int pw    = pwi[r * NN + n];
    int prop1 = Z[r * NN + pw];         // random-in-row: L1 hit
    int pt    = ptop[r * NN + n];
    float2 uu = ((const float2*)u)[(size_t)r * NN + n];

    const float* prow = phi + ((size_t)t * V + w) * K;
    float f1 = prow[prop1];             // scattered gathers, in flight during eta
    float f0 = prow[pre];

    float cdk = 0.0f;
    if (n < 64) {
        // ---- eta SGLD update for this row, wave 0 only ----
        float x = eta[r * K + n];
        float m = x;
        #pragma unroll
        for (int off = 32; off >= 1; off >>= 1)
            m = fmaxf(m, __shfl_xor(m, off, 64));
        float e = expf(x - m);
        float s = e;
        #pragma unroll
        for (int off = 32; off >= 1; off >>= 1)
            s += __shfl_xor(s, off, 64);
        float smx = e / s;
        cdk = CDK[r * K + n];
        float grad  = cdk - (float)NN * smx;
        float prior = alpha[t * K + n] - x;          // ETA_VAR = 1
        float en = x + 0.005f * (grad + prior) + noise_eta[r] * 0.01f;
        esh[n] = en;
        eta_new[r * K + n] = en;
    } else if (n < 128) {
        hist[n - 64] = 0;
    } else if (n < 128 + NB) {
        bcnt[n - 128] = 0;
    }
    __syncthreads();

    float a1 = jexp(f1) / jexp(f0);
    int k1 = (uu.x < a1) ? prop1 : pre;

    float a2 = jexp(esh[pt]) / jexp(esh[k1]);
    int z = (uu.y < a2) ? pt : k1;

    // LDS-only work before barriers
    atomicAdd(&hist[z], 1);
    atomicAdd(&hist[pre], -1);

    int keep = (z != pre);
    int bucket = w / 1000;              // 0..31, 1000-word ranges
    int myidx = 0;
    if (keep) myidx = atomicAdd(&bcnt[bucket], 1);
    __syncthreads();

    if (n < NB) {
        // one small global reservation atomic per (block,bucket); 2048 counters
        bbase[n] = (int)atomicAdd(&resv[(t * NB + n) * 16 + slice],
                                  (unsigned int)bcnt[n]);
    }
    __syncthreads();

    // ---- phase C: global writes, fire-and-forget ----
    z_out[r * NN + n] = (float)z;
    if (keep) {
        int slot = bbase[bucket] + myidx;
        if (slot < CAP) {
            unsigned int pk = (unsigned int)w | ((unsigned int)z << 15) |
                              ((unsigned int)pre << 21);
            list[(size_t)((t * NB + bucket) * 16 + slice) * CAP + slot] = pk;
        }
    }
    if (n < K) {
        CDK_new[r * K + n] = cdk + (float)hist[n];   // block owns this row
    }
}

// ---------------- S finalize + CK_new += sum_d (CDKn - CDK) ----------------
// grid = 64 blocks (16 per t), 256 threads; CK_new pre-initialized with CK.
__global__ void reduce_kernel(const float* __restrict__ S_part,
                              const float* __restrict__ CDKn,
                              const float* __restrict__ CDK,
                              float* __restrict__ S,
                              float* __restrict__ CK_new)
{
    int b = blockIdx.x;
    int tid = threadIdx.x;

    if (b < 4 && tid < 64) {            // S finalize for t = b
        float s = 0.0f;
        #pragma unroll 5
        for (int i = 0; i < 125; ++i)
            s += S_part[(b * 125 + i) * 64 + tid];
        S[b * 64 + tid] = s;
    }

    int t  = b >> 4;
    int k  = tid & 63;
    int dl = tid >> 6;                  // 0..3
    int dbase = (b & 15) << 6;          // 16 chunks of 64 d's per t
    float s = 0.0f;
    #pragma unroll
    for (int i = 0; i < 16; ++i) {
        int d = dbase + dl + (i << 2);
        size_t idx = ((size_t)(t << 10) + d) * 64 + k;
        s += CDKn[idx] - CDK[idx];
    }
    __shared__ float sm[256];
    sm[tid] = s;
    __syncthreads();
    if (tid < 64) {
        float tot = sm[k] + sm[k + 64] + sm[k + 128] + sm[k + 192];
        if (tot != 0.0f) atomicAdd(&CK_new[(t << 6) + k], tot);
    }
}

// ---------------- merged: list replay (all 4 t) + phi SGLD + CWK_new ----------------
// grid = 256 blocks x 1024 THREADS (16 waves/CU = 50% occupancy; R12's 256-thread
// version was latency-starved at 12.5% ceiling).
// bucket = b&31, window = b>>5; b%8 = bucket%8 -> windows of one bucket share an XCD.
// LDS: 4 x (plus,minus) histograms of 125 rows x 16 u32 = 64000 B.
__global__ void cwkphi_kernel(const unsigned int* __restrict__ list,
                              const unsigned int* __restrict__ resv,
                              const float* __restrict__ CWK,
                              const float* __restrict__ phi,
                              const float* __restrict__ CKn,
                              const float* __restrict__ S,
                              const float* __restrict__ noise_phi,
                              float* __restrict__ CWK_new,
                              float* __restrict__ phi_new)
{
    int b = blockIdx.x;
    int bucket = b & 31;
    int window = b >> 5;                // 0..7
    int vbase = bucket * 1000 + window * 125;

    __shared__ unsigned int plusH[4][2000];     // [t][row*16 + kg], u8 x4 packed
    __shared__ unsigned int minusH[4][2000];
    for (int i = threadIdx.x; i < 2000; i += 1024) {
        plusH[0][i] = 0u; plusH[1][i] = 0u; plusH[2][i] = 0u; plusH[3][i] = 0u;
        minusH[0][i] = 0u; minusH[1][i] = 0u; minusH[2][i] = 0u; minusH[3][i] = 0u;
    }
    __syncthreads();

    int wave = threadIdx.x >> 6;        // 0..15
    int lane = threadIdx.x & 63;

#define DECODE(PK, TT) {                                                          \
        int wv = (int)((PK) & 32767u);                                            \
        unsigned int vl = (unsigned int)(wv - vbase);                             \
        if (vl < 125u) {                                                          \
            int zz = (int)(((PK) >> 15) & 63u);                                   \
            int pr = (int)(((PK) >> 21) & 63u);                                   \
            atomicAdd(&plusH [TT][vl * 16 + (zz >> 2)], 1u << ((zz & 3) * 8));    \
            atomicAdd(&minusH[TT][vl * 16 + (pr >> 2)], 1u << ((pr & 3) * 8));    \
        } }

    // 64 segments (4 t x 16 slices); 16 waves take 4 segments each
    for (int ss = wave; ss < 64; ss += 16) {
        int t = ss >> 4;
        int s = ss & 15;
        int seg = (t * NB + bucket) * 16 + s;
        int len = (int)resv[seg]; if (len > CAP) len = CAP;
        const unsigned int* lp = list + (size_t)seg * CAP;
        const uint4* lp4 = (const uint4*)lp;
        int n4 = len >> 2;
        for (int i = lane; i < n4; i += 64) {
            uint4 q = lp4[i];
            DECODE(q.x, t); DECODE(q.y, t); DECODE(q.z, t); DECODE(q.w, t);
        }
        int base4 = n4 << 2;
        if (lane < (len & 3)) { unsigned int pk = lp[base4 + lane]; DECODE(pk, t); }
    }
#undef DECODE
    __syncthreads();

    // ---- t-chained phi sweep over 125 rows x 64 k = 2000 float4 per t ----
    const float eps = 0.01f;
    const float half_eps = 0.005f;
    const float sig = 1.0f / 1.01f;             // phi_sigma / PHI_VAR

    const float4* phi4  = (const float4*)phi;
    const float4* cwk4  = (const float4*)CWK;
    const float4* ck4   = (const float4*)CKn;
    const float4* s4    = (const float4*)S;
    float4*       pout4 = (float4*)phi_new;
    float4*       cout4 = (float4*)CWK_new;

    float np0 = noise_phi[0] * eps, np1 = noise_phi[1] * eps;
    float np2 = noise_phi[2] * eps, np3 = noise_phi[3] * eps;

    size_t base4 = (size_t)vbase * 16;          // float4 offset of window within a t

    for (int i4 = threadIdx.x; i4 < 2000; i4 += 1024) {
        int kg = i4 & 15;
        size_t g = base4 + i4;

        float4 p0 = phi4[g];
        float4 p1 = phi4[g +     512000];
        float4 p2 = phi4[g + 2 * 512000];
        float4 p3 = phi4[g + 3 * 512000];

        float4 c0 = cwk4[g];
        float4 c1 = cwk4[g +     512000];
        float4 c2 = cwk4[g + 2 * 512000];
        float4 c3 = cwk4[g + 3 * 512000];

        unsigned int pl0 = plusH[0][i4], mi0 = minusH[0][i4];
        unsigned int pl1 = plusH[1][i4], mi1 = minusH[1][i4];
        unsigned int pl2 = plusH[2][i4], mi2 = minusH[2][i4];
        unsigned int pl3 = plusH[3][i4], mi3 = minusH[3][i4];

        float4 ckn0 = ck4[kg],      ckn1 = ck4[16 + kg];
        float4 ckn2 = ck4[32 + kg], ckn3 = ck4[48 + kg];
        float4 ss0 = s4[kg],        ss1 = s4[16 + kg];
        float4 ss2 = s4[32 + kg],   ss3 = s4[48 + kg];

        float4 o0, o1, o2, o3, w0, w1, w2, w3;
        #pragma unroll
        for (int j = 0; j < 4; ++j) {
            int sh = j * 8;
            float q0 = (&p0.x)[j], q1 = (&p1.x)[j], q2 = (&p2.x)[j], q3 = (&p3.x)[j];
            float cw0 = (&c0.x)[j] + (float)((pl0 >> sh) & 255u) - (float)((mi0 >> sh) & 255u);
            float cw1 = (&c1.x)[j] + (float)((pl1 >> sh) & 255u) - (float)((mi1 >> sh) & 255u);
            float cw2 = (&c2.x)[j] + (float)((pl2 >> sh) & 255u) - (float)((mi2 >> sh) & 255u);
            float cw3 = (&c3.x)[j] + (float)((pl3 >> sh) & 255u) - (float)((mi3 >> sh) & 255u);
            (&w0.x)[j] = cw0; (&w1.x)[j] = cw1; (&w2.x)[j] = cw2; (&w3.x)[j] = cw3;

            float g0 = cw0 - (&ckn0.x)[j] * (expf(q0) / (&ss0.x)[j]);
            float g1 = cw1 - (&ckn1.x)[j] * (expf(q1) / (&ss1.x)[j]);
            float g2 = cw2 - (&ckn2.x)[j] * (expf(q2) / (&ss2.x)[j]);
            float g3 = cw3 - (&ckn3.x)[j] * (expf(q3) / (&ss3.x)[j]);

            float r0 = q0 + half_eps * (g0 + 2.0f * q1 * sig - 2.0f * q0) + np0;
            float r1 = q1 + half_eps * (g1 + q2 + r0 - 2.0f * q1)         + np1;
            float r2 = q2 + half_eps * (g2 + q3 + r1 - 2.0f * q2)         + np2;
            float r3 = q3 + half_eps * (g3 + r2 - q3)                      + np3;

            (&o0.x)[j] = r0; (&o1.x)[j] = r1; (&o2.x)[j] = r2; (&o3.x)[j] = r3;
        }

        pout4[g]              = o0;
        pout4[g +     512000] = o1;
        pout4[g + 2 * 512000] = o2;
        pout4[g + 3 * 512000] = o3;

        cout4[g]              = w0;
        cout4[g +     512000] = w1;
        cout4[g + 2 * 512000] = w2;
        cout4[g + 3 * 512000] = w3;
    }
}

extern "C" void kernel_launch(void* const* d_in, const int* in_sizes, int n_in,
                              void* d_out, int out_size, void* d_ws, size_t ws_size,
                              hipStream_t stream)
{
    const int*   W         = (const int*)  d_in[0];
    const int*   Z         = (const int*)  d_in[1];
    const int*   pwi       = (const int*)  d_in[2];
    const int*   ptop      = (const int*)  d_in[3];
    const float* u_mh      = (const float*)d_in[4];
    const float* noise_eta = (const float*)d_in[5];
    const float* noise_phi = (const float*)d_in[6];
    const float* alpha     = (const float*)d_in[7];
    const float* phi       = (const float*)d_in[8];
    const float* eta       = (const float*)d_in[9];
    const float* CDK       = (const float*)d_in[10];
    const float* CWK       = (const float*)d_in[11];
    const float* CK        = (const float*)d_in[12];

    float* out     = (float*)d_out;
    float* eta_new = out;                               // T*D*K   = 262144
    float* phi_new = out + 262144;                      // T*V*K   = 8192000
    float* CDK_new = out + 8454144;                     // T*D*K   = 262144
    float* CWK_new = out + 8716288;                     // T*V*K   = 8192000
    float* CK_new  = out + 16908288;                    // T*K     = 256
    float* z_out   = out + 16908544;                    // T*D*N   = 1048576

    float* ws      = (float*)d_ws;
    float* S       = ws;                                // 256 floats
    float* S_part  = ws + 256;                          // 500*64 floats
    unsigned int* resv = (unsigned int*)(ws + 256 + 32000);    // 2048 u32
    unsigned int* list = resv + 2048;                          // 2048*CAP u32 = 8MB

    hipMemsetAsync(resv, 0, 2048 * sizeof(unsigned int), stream);

    fused_kernel<<<500 + TD, 256, 0, stream>>>(W, Z, pwi, ptop, u_mh, phi,
                                               eta, alpha, noise_eta, CDK, CK,
                                               S_part, CK_new,
                                               eta_new, CDK_new, resv, list, z_out);
    reduce_kernel<<<64, 256, 0, stream>>>(S_part, CDK_new, CDK, S, CK_new);
    cwkphi_kernel<<<256, 1024, 0, stream>>>(list, resv, CWK, phi, CK_new, S,
                                            noise_phi, CWK_new, phi_new);
}